// Round 8
// baseline (68.779 us; speedup 1.0000x reference)
//
#include <hip/hip_runtime.h>
#include <cstdint>
#include <cstddef>

#define CCH   512
#define FSCOPE 27
#define HWSP  3136
#define NBATCH 16
#define NCOL  (NBATCH*HWSP)   // 50176

#define BMT 128               // rows per block (H panel in LDS)
#define BCT 256               // cols per block (8 waves x 32 cols)

#define PI_F 3.14159265358979323846f

typedef __bf16 bf16x8 __attribute__((ext_vector_type(8)));
typedef float  f32x4  __attribute__((ext_vector_type(4)));

static __device__ __forceinline__ unsigned short f2bf(float f) {
  unsigned u = __builtin_bit_cast(unsigned, f);
  unsigned r = 0x7FFFu + ((u >> 16) & 1u);
  return (unsigned short)((u + r) >> 16);
}

// ---- kernel 1 (fused fk + inverse DFT, parallel over d):
__global__ __launch_bounds__(512)
void k_h2(const float* __restrict__ w, float* __restrict__ h) {
  __shared__ float red[8];
  const int d = blockIdx.x;
  const int m = threadIdx.x;

  float re = 1.0f, im = 0.0f;
  #pragma unroll
  for (int j = 0; j < FSCOPE; ++j) {
    int t = (m * (j - FSCOPE/2)) % CCH;
    if (t < 0) t += CCH;
    float ang = (2.0f * PI_F / CCH) * (float)t;
    float s, c;
    sincosf(ang, &s, &c);
    float wj = w[j];
    re -= wj * c;
    im += wj * s;
  }

  int t = (m * d) & (CCH - 1);
  float ang = (2.0f * PI_F / CCH) * (float)t;
  float s, c;
  sincosf(ang, &s, &c);
  float inv = 1.0f / (re * re + im * im);
  float term = (c * re + s * im) * inv;

  #pragma unroll
  for (int off = 32; off > 0; off >>= 1)
    term += __shfl_down(term, off, 64);

  const int lane = m & 63, wv = m >> 6;
  if (lane == 0) red[wv] = term;
  __syncthreads();
  if (m == 0) {
    float tot = 0.f;
    #pragma unroll
    for (int i = 0; i < 8; ++i) tot += red[i];
    h[d] = tot / (float)CCH;
  }
}

// ---- kernel 2: H[m][k] = bf16( h[(m-k) mod 512] ), row-major 512x512
__global__ void k_buildH(const float* __restrict__ h, unsigned short* __restrict__ Hm) {
  int m = blockIdx.x;
  for (int k = threadIdx.x; k < CCH; k += blockDim.x) {
    Hm[m*CCH + k] = f2bf(h[(m - k) & (CCH - 1)]);
  }
}

// LOADB: raw f32 X loads for K-step ks into named buffer (reg prefetch)
#define LOADB(ks, buf)                                              \
  { const int k0_ = (ks) * 32 + kq * 8;                             \
    _Pragma("unroll")                                               \
    for (int cs = 0; cs < 2; ++cs) {                                \
      _Pragma("unroll")                                             \
      for (int j = 0; j < 8; ++j)                                   \
        buf[cs][j] = xb[cs][(size_t)(k0_ + j) * HWSP];              \
    } }

// COMPUTE: cvt buffer -> bf16 frags, 8 swizzled ds_reads, 16 MFMAs
#define COMPUTE(ks, buf)                                                      \
  { bf16x8 pb0, pb1;                                                          \
    { union { __bf16 hh[8]; bf16x8 v; } u;                                    \
      _Pragma("unroll")                                                       \
      for (int j = 0; j < 8; ++j) u.hh[j] = (__bf16)buf[0][j];                \
      pb0 = u.v; }                                                            \
    { union { __bf16 hh[8]; bf16x8 v; } u;                                    \
      _Pragma("unroll")                                                       \
      for (int j = 0; j < 8; ++j) u.hh[j] = (__bf16)buf[1][j];                \
      pb1 = u.v; }                                                            \
    const int kb_ = (((ks) >> 1) << 7) + ((((((ks) & 1) << 2) | kq) ^ rw) << 4); \
    _Pragma("unroll")                                                         \
    for (int fm = 0; fm < 8; ++fm) {                                          \
      bf16x8 af = *reinterpret_cast<const bf16x8*>(Al + aBase[fm] + kb_);     \
      acc[fm][0] = __builtin_amdgcn_mfma_f32_16x16x32_bf16(af, pb0, acc[fm][0], 0, 0, 0); \
      acc[fm][1] = __builtin_amdgcn_mfma_f32_16x16x32_bf16(af, pb1, acc[fm][1], 0, 0, 0); \
    } }

// ---- kernel 3: Y = H * X, barrier-free streaming GEMM.
// Block: H rows [m0,m0+128) in 128KB LDS (loaded once, then read-only);
// 8 waves x 32 cols each stream X from global with 2-stage reg prefetch.
// grid = 4 m-tiles * 196 col-tiles = 784 blocks, 512 threads.
__global__ __launch_bounds__(512, 2)
void k_gemm(const float* __restrict__ X, const unsigned short* __restrict__ Hm,
            float* __restrict__ Y) {
  __shared__ __align__(16) unsigned char Al[BMT * 1024];   // 128 KB

  const int tid  = threadIdx.x;
  const int lane = tid & 63;
  const int w    = tid >> 6;       // 0..7
  const int r15  = lane & 15;
  const int kq   = lane >> 4;      // 0..3
  const int rw   = r15 & 7;

  // XCD-aware swizzle (784 = 8 * 98, bijective); m-tile fastest so the 4
  // blocks sharing a col-tile (same X cols) land on the same XCD's L2.
  int bid = blockIdx.x;
  int cpx = gridDim.x >> 3;        // 98
  int swz = (bid & 7) * cpx + (bid >> 3);
  const int tm = swz & 3;
  const int tc = swz >> 2;         // 0..195
  const int m0 = tm * BMT;
  const int j0 = tc * BCT;

  // ---- prologue: H panel -> LDS via global_load_lds.
  // Wave-uniform dst row*1024 (+lane*16 by HW); lane's global chunk
  // pre-swizzled: cgl = (lane&56)|((lane&7)^(row&7))  (involution).
  #pragma unroll
  for (int i = 0; i < 16; ++i) {
    int r = w * 16 + i;
    int cgl = (lane & 56) | ((lane & 7) ^ (r & 7));
    const unsigned short* src = Hm + (size_t)(m0 + r) * CCH + cgl * 8;
    __builtin_amdgcn_global_load_lds(
        (const __attribute__((address_space(1))) void*)src,
        (__attribute__((address_space(3))) void*)(Al + r * 1024), 16, 0, 0);
  }
  __syncthreads();   // the only barrier; LDS read-only afterwards

  // a-frag row bases (swizzled chunk offset added per K-step)
  int aBase[8];
  #pragma unroll
  for (int fm = 0; fm < 8; ++fm) aBase[fm] = (fm * 16 + r15) * 1024;

  // per-lane column base pointers (cols may straddle batch boundary)
  const float* xb[2];
  float*       yb[2];
  #pragma unroll
  for (int cs = 0; cs < 2; ++cs) {
    int colg = j0 + w * 32 + cs * 16 + r15;
    int n = colg / HWSP;
    int s = colg - n * HWSP;
    xb[cs] = X + (size_t)n * (CCH * (size_t)HWSP) + s;
    yb[cs] = Y + (size_t)n * (CCH * (size_t)HWSP) + s;
  }

  f32x4 acc[8][2];
  #pragma unroll
  for (int i = 0; i < 8; ++i) {
    acc[i][0] = (f32x4){0.f, 0.f, 0.f, 0.f};
    acc[i][1] = (f32x4){0.f, 0.f, 0.f, 0.f};
  }

  float bufA[2][8], bufB[2][8];    // named stages (no dynamic indexing)
  LOADB(0, bufA);

  for (int kp = 0; kp < 8; ++kp) {           // 16 K-steps, 2 per iter
    LOADB(kp * 2 + 1, bufB);                 // prefetch odd step
    COMPUTE(kp * 2, bufA);
    if (kp < 7) LOADB(kp * 2 + 2, bufA);     // prefetch next even step
    COMPUTE(kp * 2 + 1, bufB);
  }

  // ---- epilogue: C/D layout col = lane&15, row = kq*4 + r (m89/m91)
  #pragma unroll
  for (int fm = 0; fm < 8; ++fm) {
    #pragma unroll
    for (int cs = 0; cs < 2; ++cs) {
      float* yp = yb[cs] + (size_t)(m0 + fm * 16 + kq * 4) * HWSP;
      #pragma unroll
      for (int r = 0; r < 4; ++r)
        yp[(size_t)r * HWSP] = acc[fm][cs][r];
    }
  }
}

extern "C" void kernel_launch(void* const* d_in, const int* in_sizes, int n_in,
                              void* d_out, int out_size, void* d_ws, size_t ws_size,
                              hipStream_t stream) {
  const float* X = (const float*)d_in[0];   // [16,512,56,56] f32
  const float* w = (const float*)d_in[1];   // [27] f32
  float* Y = (float*)d_out;

  float* h           = (float*)d_ws;                                // 2 KB
  unsigned short* Hm = (unsigned short*)((char*)d_ws + 4096);       // 512 KB

  k_h2    <<<CCH, 512, 0, stream>>>(w, h);
  k_buildH<<<CCH, 256, 0, stream>>>(h, Hm);

  const int nblk = (CCH / BMT) * (NCOL / BCT);   // 4 * 196 = 784
  k_gemm  <<<nblk, 512, 0, stream>>>(X, Hm, Y);
}